// Round 3
// baseline (746.179 us; speedup 1.0000x reference)
//
#include <hip/hip_runtime.h>
#include <hip/hip_bf16.h>

#define IN_F 128
#define OUT_F 32
#define NPB 256            // nodes per bucket (dst >> 8)
#define CHUNK 8192         // edges per binning block
#define K2_THREADS 512
#define K3_THREADS 1024

static __device__ inline unsigned short f2bf_rne(float f) {
    unsigned u = __float_as_uint(f);
    unsigned r = u + 0x7FFF + ((u >> 16) & 1);   // round-to-nearest-even
    return (unsigned short)(r >> 16);
}

// ---------------- K1: h = x @ W, output bf16 (W staged in LDS) ----------------
__global__ void gcn_gemm_h(const float* __restrict__ x, const float* __restrict__ W,
                           unsigned short* __restrict__ h, int n_rows)
{
    __shared__ float Wl[IN_F * OUT_F];           // 16 KB
    const int tid = threadIdx.x;
    const float4* W4 = (const float4*)W;
    float4* Wl4 = (float4*)Wl;
    #pragma unroll
    for (int i = 0; i < 4; ++i)
        Wl4[tid + i * 256] = W4[tid + i * 256];
    __syncthreads();

    const int c4   = tid & 7;
    const int rloc = tid >> 3;
    const int row  = blockIdx.x * 32 + rloc;
    if (row >= n_rows) return;

    const float4* xr = (const float4*)(x + (size_t)row * IN_F);
    float4 acc = {0.f, 0.f, 0.f, 0.f};
    #pragma unroll
    for (int k4 = 0; k4 < IN_F / 4; ++k4) {
        const float4 xv = xr[k4];
        #pragma unroll
        for (int j = 0; j < 4; ++j) {
            const int k = k4 * 4 + j;
            const float4 wv = *(const float4*)(&Wl[k * OUT_F + c4 * 4]);
            const float xs = (&xv.x)[j];
            acc.x += xs * wv.x;
            acc.y += xs * wv.y;
            acc.z += xs * wv.z;
            acc.w += xs * wv.w;
        }
    }
    ushort4 o = { f2bf_rne(acc.x), f2bf_rne(acc.y), f2bf_rne(acc.z), f2bf_rne(acc.w) };
    *(ushort4*)(&h[(size_t)row * OUT_F + c4 * 4]) = o;
}

// ---------------- K2: per-chunk counting sort into coarse buckets ----------------
// Each block: 8192-edge chunk -> histogram over nb buckets -> local scan ->
// grouped write into its OWN contiguous 64KB region (L2-absorbed, dense lines).
// Record: {src | (dstLocal<<17), w_bits}  (src<2^17, dstLocal<2^8)
__global__ __launch_bounds__(K2_THREADS)
void gcn_bin(const int* __restrict__ esrc, const int* __restrict__ edst,
             const float* __restrict__ ew,
             int2* __restrict__ recs, int* __restrict__ table,
             int n_edges, int nb)
{
    __shared__ int hist[512];
    __shared__ int scan[512];
    const int tid  = threadIdx.x;
    const int base = blockIdx.x * CHUNK;
    const int count = min(CHUNK, n_edges - base);

    hist[tid] = 0;
    __syncthreads();

    for (int i = tid; i < count; i += K2_THREADS)
        atomicAdd(&hist[edst[base + i] >> 8], 1);
    __syncthreads();

    // exclusive scan over 512 entries (Hillis-Steele)
    const int v = hist[tid];
    scan[tid] = v;
    __syncthreads();
    for (int off = 1; off < 512; off <<= 1) {
        int t = (tid >= off) ? scan[tid - off] : 0;
        __syncthreads();
        scan[tid] += t;
        __syncthreads();
    }
    const int excl = scan[tid] - v;

    int* trow = table + (size_t)blockIdx.x * (nb + 1);
    if (tid < nb) trow[tid] = excl;
    if (tid == 0) trow[nb] = count;

    hist[tid] = excl;          // reuse as cursor
    __syncthreads();

    for (int i = tid; i < count; i += K2_THREADS) {
        const int e = base + i;
        const int d = edst[e];
        const int pos = atomicAdd(&hist[d >> 8], 1);
        recs[(size_t)base + pos] =
            make_int2(esrc[e] | ((d & (NPB - 1)) << 17), __float_as_int(ew[e]));
    }
}

// ---------------- K3: one block per bucket, LDS fp32 accumulation ----------------
__global__ __launch_bounds__(K3_THREADS)
void gcn_aggregate(const unsigned short* __restrict__ h,
                   const int2* __restrict__ recs,
                   const int* __restrict__ table,
                   float* __restrict__ out,
                   int n_nodes, int nb, int n_chunks)
{
    __shared__ float acc[NPB * OUT_F];           // 32 KB
    const int tid = threadIdx.x;
    const int b   = blockIdx.x;

    for (int i = tid; i < NPB * OUT_F; i += K3_THREADS) acc[i] = 0.f;
    __syncthreads();

    const int wave = tid >> 6;       // 16 waves
    const int lane = tid & 63;
    const int g    = lane >> 5;      // 2 edge-groups per wave
    const int c    = lane & 31;      // channel

    for (int blk = wave; blk < n_chunks; blk += (K3_THREADS / 64)) {
        const int* trow = table + (size_t)blk * (nb + 1);
        const int s = trow[b];
        const int e = trow[b + 1];
        const size_t regBase = (size_t)blk * CHUNK;
        for (int i = s + g; i < e; i += 2) {
            const int2 r = recs[regBase + i];
            const int   src = r.x & 0x1FFFF;
            const int   dL  = (r.x >> 17) & (NPB - 1);
            const float w   = __int_as_float(r.y);
            const float hv  = __uint_as_float((unsigned)h[(size_t)src * OUT_F + c] << 16);
            atomicAdd(&acc[dL * OUT_F + c], w * hv);   // ds_add_f32
        }
    }
    __syncthreads();

    const int   nodeBase = b * NPB;
    const int   validF   = (min(NPB, n_nodes - nodeBase)) * OUT_F;
    const size_t outBase = (size_t)nodeBase * OUT_F;
    for (int i = tid; i < (NPB * OUT_F) / 4; i += K3_THREADS) {
        if (i * 4 < validF)
            *(float4*)(out + outBase + i * 4) = *(const float4*)(acc + i * 4);
    }
}

// ---------------- Fallback (no/small ws): fused, atomics into out ----------------
__global__ void gcn_fused_fallback(const float* __restrict__ x, const float* __restrict__ W,
                                   const int* __restrict__ esrc,
                                   const int* __restrict__ edst,
                                   const float* __restrict__ ew,
                                   float* __restrict__ out,
                                   long long total_units)
{
    __shared__ float Wl[IN_F * OUT_F];
    const int tid = threadIdx.x;
    const float4* W4 = (const float4*)W;
    float4* Wl4 = (float4*)Wl;
    #pragma unroll
    for (int i = 0; i < 4; ++i)
        Wl4[tid + i * 256] = W4[tid + i * 256];
    __syncthreads();

    long long u = (long long)blockIdx.x * blockDim.x + threadIdx.x;
    if (u >= total_units) return;
    const int e = (int)(u >> 5);
    const int c = (int)(u & 31);
    const int s  = esrc[e];
    const int d  = edst[e];
    const float w = ew[e];

    const float4* xr = (const float4*)(x + (size_t)s * IN_F);
    float acc = 0.f;
    #pragma unroll
    for (int k4 = 0; k4 < IN_F / 4; ++k4) {
        const float4 xv = xr[k4];
        acc += xv.x * Wl[(k4 * 4 + 0) * OUT_F + c];
        acc += xv.y * Wl[(k4 * 4 + 1) * OUT_F + c];
        acc += xv.z * Wl[(k4 * 4 + 2) * OUT_F + c];
        acc += xv.w * Wl[(k4 * 4 + 3) * OUT_F + c];
    }
    atomicAdd(out + (size_t)d * OUT_F + c, w * acc);
}

static inline size_t align_up(size_t v, size_t a) { return (v + a - 1) & ~(a - 1); }

extern "C" void kernel_launch(void* const* d_in, const int* in_sizes, int n_in,
                              void* d_out, int out_size, void* d_ws, size_t ws_size,
                              hipStream_t stream)
{
    const float* x  = (const float*)d_in[0];
    const float* W  = (const float*)d_in[1];
    const int* esrc = (const int*)d_in[2];
    const int* edst = (const int*)d_in[3];
    const float* ew = (const float*)d_in[4];
    float* out = (float*)d_out;

    const int n_nodes = in_sizes[0] / IN_F;
    const int n_edges = in_sizes[2];

    const int nb       = (n_nodes + NPB - 1) / NPB;       // 391
    const int n_chunks = (n_edges + CHUNK - 1) / CHUNK;   // 391

    const size_t h_bytes    = align_up((size_t)n_nodes * OUT_F * sizeof(unsigned short), 256);
    const size_t recs_bytes = align_up((size_t)n_chunks * CHUNK * sizeof(int2), 256);
    const size_t tab_bytes  = align_up((size_t)n_chunks * (nb + 1) * sizeof(int), 256);
    const size_t need = h_bytes + recs_bytes + tab_bytes;

    if (ws_size >= need && nb <= 511) {
        char* p = (char*)d_ws;
        unsigned short* h = (unsigned short*)p;  p += h_bytes;
        int2* recs        = (int2*)p;            p += recs_bytes;
        int*  table       = (int*)p;

        const int gemm_blocks = (n_nodes + 31) / 32;
        gcn_gemm_h<<<gemm_blocks, 256, 0, stream>>>(x, W, h, n_nodes);

        gcn_bin<<<n_chunks, K2_THREADS, 0, stream>>>(esrc, edst, ew, recs, table,
                                                     n_edges, nb);

        gcn_aggregate<<<nb, K3_THREADS, 0, stream>>>(h, recs, table, out,
                                                     n_nodes, nb, n_chunks);
    } else {
        hipMemsetAsync(d_out, 0, (size_t)out_size * sizeof(float), stream);
        const long long total_units = (long long)n_edges * 32;
        const int fblocks = (int)((total_units + 255) / 256);
        gcn_fused_fallback<<<fblocks, 256, 0, stream>>>(x, W, esrc, edst, ew, out, total_units);
    }
}

// Round 4
// 735.352 us; speedup vs baseline: 1.0147x; 1.0147x over previous
//
#include <hip/hip_runtime.h>
#include <hip/hip_bf16.h>

#define IN_F 128
#define OUT_F 32
#define NPB 256            // nodes per bucket (dst >> 8)
#define CHUNK 8192         // edges per chunk
#define BIN_THREADS 512
#define AGG_THREADS 1024
#define ACC_STRIDE 33      // +1 pad: bank = (dL + c) & 31, spreads scatter

static __device__ inline unsigned short f2bf_rne(float f) {
    unsigned u = __float_as_uint(f);
    unsigned r = u + 0x7FFF + ((u >> 16) & 1);   // round-to-nearest-even
    return (unsigned short)(r >> 16);
}

// ---------------- K1: h = x @ W, output bf16 (W staged in LDS) ----------------
__global__ void gcn_gemm_h(const float* __restrict__ x, const float* __restrict__ W,
                           unsigned short* __restrict__ h, int n_rows)
{
    __shared__ float Wl[IN_F * OUT_F];           // 16 KB
    const int tid = threadIdx.x;
    const float4* W4 = (const float4*)W;
    float4* Wl4 = (float4*)Wl;
    #pragma unroll
    for (int i = 0; i < 4; ++i)
        Wl4[tid + i * 256] = W4[tid + i * 256];
    __syncthreads();

    const int c4   = tid & 7;
    const int rloc = tid >> 3;
    const int row  = blockIdx.x * 32 + rloc;
    if (row >= n_rows) return;

    const float4* xr = (const float4*)(x + (size_t)row * IN_F);
    float4 acc = {0.f, 0.f, 0.f, 0.f};
    #pragma unroll
    for (int k4 = 0; k4 < IN_F / 4; ++k4) {
        const float4 xv = xr[k4];
        #pragma unroll
        for (int j = 0; j < 4; ++j) {
            const int k = k4 * 4 + j;
            const float4 wv = *(const float4*)(&Wl[k * OUT_F + c4 * 4]);
            const float xs = (&xv.x)[j];
            acc.x += xs * wv.x;
            acc.y += xs * wv.y;
            acc.z += xs * wv.z;
            acc.w += xs * wv.w;
        }
    }
    ushort4 o = { f2bf_rne(acc.x), f2bf_rne(acc.y), f2bf_rne(acc.z), f2bf_rne(acc.w) };
    *(ushort4*)(&h[(size_t)row * OUT_F + c4 * 4]) = o;
}

// ---------------- K2a: per-chunk histogram over buckets ----------------
__global__ __launch_bounds__(BIN_THREADS)
void gcn_count(const int* __restrict__ edst, int* __restrict__ cntT,
               int n_edges, int nb, int n_chunks)
{
    __shared__ int hist[512];
    const int tid = threadIdx.x;
    const int k   = blockIdx.x;
    const int base  = k * CHUNK;
    const int count = min(CHUNK, n_edges - base);
    hist[tid] = 0;
    __syncthreads();
    for (int i = tid; i < count; i += BIN_THREADS)
        atomicAdd(&hist[edst[base + i] >> 8], 1);
    __syncthreads();
    if (tid < nb) cntT[(size_t)tid * n_chunks + k] = hist[tid];
}

// ---------------- K2b: per-bucket exclusive scan over chunks ----------------
__global__ __launch_bounds__(512)
void gcn_scan_bucket(const int* __restrict__ cntT, int* __restrict__ offT,
                     int* __restrict__ totals, int n_chunks)
{
    __shared__ int sh[512];
    const int b = blockIdx.x, tid = threadIdx.x;
    const int v = (tid < n_chunks) ? cntT[(size_t)b * n_chunks + tid] : 0;
    sh[tid] = v;
    __syncthreads();
    for (int off = 1; off < 512; off <<= 1) {
        int t = (tid >= off) ? sh[tid - off] : 0;
        __syncthreads();
        sh[tid] += t;
        __syncthreads();
    }
    if (tid < n_chunks) offT[(size_t)b * n_chunks + tid] = sh[tid] - v;
    if (tid == 511) totals[b] = sh[511];
}

// ---------------- K2c: exclusive scan of bucket totals -> colStart ----------------
__global__ __launch_bounds__(512)
void gcn_scan_total(const int* __restrict__ totals, int* __restrict__ colStart,
                    int nb, int n_edges)
{
    __shared__ int sh[512];
    const int tid = threadIdx.x;
    const int v = (tid < nb) ? totals[tid] : 0;
    sh[tid] = v;
    __syncthreads();
    for (int off = 1; off < 512; off <<= 1) {
        int t = (tid >= off) ? sh[tid - off] : 0;
        __syncthreads();
        sh[tid] += t;
        __syncthreads();
    }
    if (tid < nb) colStart[tid] = sh[tid] - v;
    if (tid == 0) colStart[nb] = n_edges;
}

// ---------------- K2d: write records to final bucket-major slots ----------------
// Record: {src | (dstLocal<<17), w_bits}  (src < 2^17, dstLocal < 2^8)
__global__ __launch_bounds__(BIN_THREADS)
void gcn_bin(const int* __restrict__ esrc, const int* __restrict__ edst,
             const float* __restrict__ ew,
             const int* __restrict__ colStart, const int* __restrict__ offT,
             int2* __restrict__ recs, int n_edges, int nb, int n_chunks)
{
    __shared__ int cursor[512];
    const int tid = threadIdx.x;
    const int k   = blockIdx.x;
    for (int i = tid; i < nb; i += BIN_THREADS)
        cursor[i] = colStart[i] + offT[(size_t)i * n_chunks + k];
    __syncthreads();

    const int base  = k * CHUNK;
    const int count = min(CHUNK, n_edges - base);
    for (int i = tid; i < count; i += BIN_THREADS) {
        const int e = base + i;
        const int d = edst[e];
        const int pos = atomicAdd(&cursor[d >> 8], 1);
        recs[pos] = make_int2(esrc[e] | ((d & (NPB - 1)) << 17), __float_as_int(ew[e]));
    }
}

// ---------------- K3: one block per bucket, contiguous recs, LDS fp32 acc ----------------
__global__ __launch_bounds__(AGG_THREADS)
void gcn_aggregate(const unsigned short* __restrict__ h,
                   const int2* __restrict__ recs,
                   const int* __restrict__ colStart,
                   float* __restrict__ out, int n_nodes)
{
    __shared__ float acc[NPB * ACC_STRIDE];      // 33.8 KB
    const int b   = blockIdx.x;
    const int tid = threadIdx.x;

    for (int i = tid; i < NPB * ACC_STRIDE; i += AGG_THREADS) acc[i] = 0.f;
    __syncthreads();

    const int s = colStart[b];
    const int cnt = colStart[b + 1] - s;

    // one edge per thread per iteration — all iterations independent
    for (int u = tid; u < cnt; u += AGG_THREADS) {
        const int2 r  = recs[s + u];
        const int src = r.x & 0x1FFFF;
        const int dL  = (r.x >> 17) & (NPB - 1);
        const float w = __int_as_float(r.y);
        const uint4* hp = (const uint4*)(h + (size_t)src * OUT_F);  // 64B row
        float* ap = acc + dL * ACC_STRIDE;
        #pragma unroll
        for (int q = 0; q < 4; ++q) {
            const uint4 hv = hp[q];
            const int c0 = q * 8;
            atomicAdd(ap + c0 + 0, w * __uint_as_float(hv.x << 16));
            atomicAdd(ap + c0 + 1, w * __uint_as_float(hv.x & 0xFFFF0000u));
            atomicAdd(ap + c0 + 2, w * __uint_as_float(hv.y << 16));
            atomicAdd(ap + c0 + 3, w * __uint_as_float(hv.y & 0xFFFF0000u));
            atomicAdd(ap + c0 + 4, w * __uint_as_float(hv.z << 16));
            atomicAdd(ap + c0 + 5, w * __uint_as_float(hv.z & 0xFFFF0000u));
            atomicAdd(ap + c0 + 6, w * __uint_as_float(hv.w << 16));
            atomicAdd(ap + c0 + 7, w * __uint_as_float(hv.w & 0xFFFF0000u));
        }
    }
    __syncthreads();

    const int nodeBase = b * NPB;
    const int nvalid   = min(NPB, n_nodes - nodeBase);
    for (int i = tid; i < nvalid * OUT_F; i += AGG_THREADS) {
        const int node = i >> 5, c = i & 31;
        out[(size_t)(nodeBase + node) * OUT_F + c] = acc[node * ACC_STRIDE + c];
    }
}

// ---------------- Fallback (no/small ws): fused, atomics into out ----------------
__global__ void gcn_fused_fallback(const float* __restrict__ x, const float* __restrict__ W,
                                   const int* __restrict__ esrc,
                                   const int* __restrict__ edst,
                                   const float* __restrict__ ew,
                                   float* __restrict__ out,
                                   long long total_units)
{
    __shared__ float Wl[IN_F * OUT_F];
    const int tid = threadIdx.x;
    const float4* W4 = (const float4*)W;
    float4* Wl4 = (float4*)Wl;
    #pragma unroll
    for (int i = 0; i < 4; ++i)
        Wl4[tid + i * 256] = W4[tid + i * 256];
    __syncthreads();

    long long u = (long long)blockIdx.x * blockDim.x + threadIdx.x;
    if (u >= total_units) return;
    const int e = (int)(u >> 5);
    const int c = (int)(u & 31);
    const int s  = esrc[e];
    const int d  = edst[e];
    const float w = ew[e];

    const float4* xr = (const float4*)(x + (size_t)s * IN_F);
    float acc = 0.f;
    #pragma unroll
    for (int k4 = 0; k4 < IN_F / 4; ++k4) {
        const float4 xv = xr[k4];
        acc += xv.x * Wl[(k4 * 4 + 0) * OUT_F + c];
        acc += xv.y * Wl[(k4 * 4 + 1) * OUT_F + c];
        acc += xv.z * Wl[(k4 * 4 + 2) * OUT_F + c];
        acc += xv.w * Wl[(k4 * 4 + 3) * OUT_F + c];
    }
    atomicAdd(out + (size_t)d * OUT_F + c, w * acc);
}

static inline size_t align_up(size_t v, size_t a) { return (v + a - 1) & ~(a - 1); }

extern "C" void kernel_launch(void* const* d_in, const int* in_sizes, int n_in,
                              void* d_out, int out_size, void* d_ws, size_t ws_size,
                              hipStream_t stream)
{
    const float* x  = (const float*)d_in[0];
    const float* W  = (const float*)d_in[1];
    const int* esrc = (const int*)d_in[2];
    const int* edst = (const int*)d_in[3];
    const float* ew = (const float*)d_in[4];
    float* out = (float*)d_out;

    const int n_nodes = in_sizes[0] / IN_F;
    const int n_edges = in_sizes[2];

    const int nb       = (n_nodes + NPB - 1) / NPB;       // 391
    const int n_chunks = (n_edges + CHUNK - 1) / CHUNK;   // 391

    const size_t h_bytes    = align_up((size_t)n_nodes * OUT_F * sizeof(unsigned short), 256);
    const size_t cnt_bytes  = align_up((size_t)nb * n_chunks * sizeof(int), 256);
    const size_t off_bytes  = align_up((size_t)nb * n_chunks * sizeof(int), 256);
    const size_t tot_bytes  = align_up((size_t)nb * sizeof(int), 256);
    const size_t col_bytes  = align_up(((size_t)nb + 1) * sizeof(int), 256);
    const size_t recs_bytes = align_up((size_t)n_edges * sizeof(int2), 256);
    const size_t need = h_bytes + cnt_bytes + off_bytes + tot_bytes + col_bytes + recs_bytes;

    if (ws_size >= need && nb <= 512 && n_chunks <= 512) {
        char* p = (char*)d_ws;
        unsigned short* h = (unsigned short*)p;  p += h_bytes;
        int* cntT     = (int*)p;                 p += cnt_bytes;
        int* offT     = (int*)p;                 p += off_bytes;
        int* totals   = (int*)p;                 p += tot_bytes;
        int* colStart = (int*)p;                 p += col_bytes;
        int2* recs    = (int2*)p;

        const int gemm_blocks = (n_nodes + 31) / 32;
        gcn_gemm_h<<<gemm_blocks, 256, 0, stream>>>(x, W, h, n_nodes);

        gcn_count<<<n_chunks, BIN_THREADS, 0, stream>>>(edst, cntT, n_edges, nb, n_chunks);
        gcn_scan_bucket<<<nb, 512, 0, stream>>>(cntT, offT, totals, n_chunks);
        gcn_scan_total<<<1, 512, 0, stream>>>(totals, colStart, nb, n_edges);
        gcn_bin<<<n_chunks, BIN_THREADS, 0, stream>>>(esrc, edst, ew, colStart, offT,
                                                      recs, n_edges, nb, n_chunks);
        gcn_aggregate<<<nb, AGG_THREADS, 0, stream>>>(h, recs, colStart, out, n_nodes);
    } else {
        hipMemsetAsync(d_out, 0, (size_t)out_size * sizeof(float), stream);
        const long long total_units = (long long)n_edges * 32;
        const int fblocks = (int)((total_units + 255) / 256);
        gcn_fused_fallback<<<fblocks, 256, 0, stream>>>(x, W, esrc, edst, ew, out, total_units);
    }
}

// Round 5
// 691.447 us; speedup vs baseline: 1.0792x; 1.0635x over previous
//
#include <hip/hip_runtime.h>
#include <hip/hip_bf16.h>

#define IN_F 128
#define OUT_F 32
#define BSHIFT 6
#define NPB 64             // nodes per bucket (dst >> 6)
#define CHUNK 8192         // edges per chunk
#define BIN_THREADS 512
#define AGG_THREADS 256
#define ACC_STRIDE 33      // bank = (dL + c) & 31 -> conflict-free per edge
#define MAXB 2048

static __device__ inline unsigned short f2bf_rne(float f) {
    unsigned u = __float_as_uint(f);
    unsigned r = u + 0x7FFF + ((u >> 16) & 1);   // round-to-nearest-even
    return (unsigned short)(r >> 16);
}

// ---------------- K1: h = x @ W, output bf16 (W staged in LDS) ----------------
__global__ void gcn_gemm_h(const float* __restrict__ x, const float* __restrict__ W,
                           unsigned short* __restrict__ h, int n_rows)
{
    __shared__ float Wl[IN_F * OUT_F];           // 16 KB
    const int tid = threadIdx.x;
    const float4* W4 = (const float4*)W;
    float4* Wl4 = (float4*)Wl;
    #pragma unroll
    for (int i = 0; i < 4; ++i)
        Wl4[tid + i * 256] = W4[tid + i * 256];
    __syncthreads();

    const int c4   = tid & 7;
    const int rloc = tid >> 3;
    const int row  = blockIdx.x * 32 + rloc;
    if (row >= n_rows) return;

    const float4* xr = (const float4*)(x + (size_t)row * IN_F);
    float4 acc = {0.f, 0.f, 0.f, 0.f};
    #pragma unroll
    for (int k4 = 0; k4 < IN_F / 4; ++k4) {
        const float4 xv = xr[k4];
        #pragma unroll
        for (int j = 0; j < 4; ++j) {
            const int k = k4 * 4 + j;
            const float4 wv = *(const float4*)(&Wl[k * OUT_F + c4 * 4]);
            const float xs = (&xv.x)[j];
            acc.x += xs * wv.x;
            acc.y += xs * wv.y;
            acc.z += xs * wv.z;
            acc.w += xs * wv.w;
        }
    }
    ushort4 o = { f2bf_rne(acc.x), f2bf_rne(acc.y), f2bf_rne(acc.z), f2bf_rne(acc.w) };
    *(ushort4*)(&h[(size_t)row * OUT_F + c4 * 4]) = o;
}

// ---------------- K2a: per-chunk histogram over buckets ----------------
__global__ __launch_bounds__(BIN_THREADS)
void gcn_count(const int* __restrict__ edst, int* __restrict__ cntT,
               int n_edges, int nb, int n_chunks)
{
    __shared__ int hist[MAXB];
    const int tid = threadIdx.x;
    const int k   = blockIdx.x;
    const int base  = k * CHUNK;
    const int count = min(CHUNK, n_edges - base);
    for (int i = tid; i < nb; i += BIN_THREADS) hist[i] = 0;
    __syncthreads();
    for (int i = tid; i < count; i += BIN_THREADS)
        atomicAdd(&hist[edst[base + i] >> BSHIFT], 1);
    __syncthreads();
    for (int i = tid; i < nb; i += BIN_THREADS)
        cntT[(size_t)i * n_chunks + k] = hist[i];      // [bucket][chunk]
}

// ---------------- K2b: per-bucket exclusive scan over chunks ----------------
__global__ __launch_bounds__(512)
void gcn_scan_bucket(const int* __restrict__ cntT, int* __restrict__ offT,
                     int* __restrict__ totals, int n_chunks, int nb)
{
    __shared__ int sh[512];
    const int b = blockIdx.x, tid = threadIdx.x;
    const int v = (tid < n_chunks) ? cntT[(size_t)b * n_chunks + tid] : 0;
    sh[tid] = v;
    __syncthreads();
    for (int off = 1; off < 512; off <<= 1) {
        int t = (tid >= off) ? sh[tid - off] : 0;
        __syncthreads();
        sh[tid] += t;
        __syncthreads();
    }
    if (tid < n_chunks) offT[(size_t)tid * nb + b] = sh[tid] - v;   // [chunk][bucket]
    if (tid == 511) totals[b] = sh[511];
}

// ---------------- K2c: exclusive scan of ROUNDED bucket totals ----------------
// colStart[b] = sum of round32(totals[i]) for i < b; pads are zero-records.
__global__ __launch_bounds__(1024)
void gcn_scan_total(const int* __restrict__ totals, int* __restrict__ colStart, int nb)
{
    __shared__ int sh[1024];
    __shared__ int carry_s;
    const int tid = threadIdx.x;
    if (tid == 0) carry_s = 0;
    __syncthreads();
    for (int base = 0; base < nb; base += 1024) {
        const int idx = base + tid;
        const int v = (idx < nb) ? ((totals[idx] + 31) & ~31) : 0;
        sh[tid] = v;
        __syncthreads();
        for (int off = 1; off < 1024; off <<= 1) {
            int t = (tid >= off) ? sh[tid - off] : 0;
            __syncthreads();
            sh[tid] += t;
            __syncthreads();
        }
        const int carry = carry_s;
        if (idx < nb) colStart[idx] = carry + sh[tid] - v;
        __syncthreads();
        if (tid == 1023) carry_s = carry + sh[1023];
        __syncthreads();
    }
    if (tid == 0) colStart[nb] = carry_s;
}

// ---------------- K2d: write records to final bucket-major slots ----------------
// Record: {src | (dstLocal<<17), w_bits}  (src < 2^17, dstLocal < 2^6)
__global__ __launch_bounds__(BIN_THREADS)
void gcn_bin(const int* __restrict__ esrc, const int* __restrict__ edst,
             const float* __restrict__ ew,
             const int* __restrict__ colStart, const int* __restrict__ offT,
             int2* __restrict__ recs, int n_edges, int nb, int n_chunks)
{
    __shared__ int cursor[MAXB];
    const int tid = threadIdx.x;
    const int k   = blockIdx.x;
    const int* offRow = offT + (size_t)k * nb;
    for (int i = tid; i < nb; i += BIN_THREADS)
        cursor[i] = colStart[i] + offRow[i];
    __syncthreads();

    const int base  = k * CHUNK;
    const int count = min(CHUNK, n_edges - base);
    for (int i = tid; i < count; i += BIN_THREADS) {
        const int e = base + i;
        const int d = edst[e];
        const int pos = atomicAdd(&cursor[d >> BSHIFT], 1);
        recs[pos] = make_int2(esrc[e] | ((d & (NPB - 1)) << 17), __float_as_int(ew[e]));
    }
}

// ---------------- K3: one block per bucket; half-wave owns one edge ----------------
// lanes 0..31 = channels; h-row read coalesced 64B; rec load half-uniform
// (broadcast); one ds_add_f32 per lane -> banks (dL+c)&31 all distinct.
__global__ __launch_bounds__(AGG_THREADS, 4)
void gcn_aggregate(const unsigned short* __restrict__ h,
                   const int2* __restrict__ recs,
                   const int* __restrict__ colStart,
                   float* __restrict__ out, int n_nodes)
{
    __shared__ float acc[NPB * ACC_STRIDE];      // 8.4 KB
    const int b   = blockIdx.x;
    const int tid = threadIdx.x;

    for (int i = tid; i < NPB * ACC_STRIDE; i += AGG_THREADS) acc[i] = 0.f;
    __syncthreads();

    const int s = colStart[b];
    const int nGroups = (colStart[b + 1] - s) >> 5;   // padded to multiple of 32
    const int hw = tid >> 5;                          // 8 half-waves
    const int c  = tid & 31;                          // channel

    for (int g = hw; g < nGroups; g += AGG_THREADS / 32) {
        const int2* rp = recs + s + g * 32;
        #pragma unroll 8
        for (int j = 0; j < 32; ++j) {
            const int2 r  = rp[j];                    // uniform per half-wave
            const int src = r.x & 0x1FFFF;
            const int dL  = (r.x >> 17) & (NPB - 1);
            const float w = __int_as_float(r.y);
            const float hv = __uint_as_float((unsigned)h[((size_t)src << 5) + c] << 16);
            atomicAdd(&acc[dL * ACC_STRIDE + c], w * hv);
        }
    }
    __syncthreads();

    const int nodeBase = b << BSHIFT;
    const int nvalid   = min(NPB, n_nodes - nodeBase);
    for (int i = tid; i < (nvalid * OUT_F) / 4; i += AGG_THREADS) {
        const int node = (i * 4) >> 5;
        const int cc   = (i * 4) & 31;
        const float* ap = acc + node * ACC_STRIDE + cc;
        float4 v = { ap[0], ap[1], ap[2], ap[3] };
        *(float4*)(out + ((size_t)(nodeBase + node) << 5) + cc) = v;
    }
}

// ---------------- Fallback (no/small ws): fused, atomics into out ----------------
__global__ void gcn_fused_fallback(const float* __restrict__ x, const float* __restrict__ W,
                                   const int* __restrict__ esrc,
                                   const int* __restrict__ edst,
                                   const float* __restrict__ ew,
                                   float* __restrict__ out,
                                   long long total_units)
{
    __shared__ float Wl[IN_F * OUT_F];
    const int tid = threadIdx.x;
    const float4* W4 = (const float4*)W;
    float4* Wl4 = (float4*)Wl;
    #pragma unroll
    for (int i = 0; i < 4; ++i)
        Wl4[tid + i * 256] = W4[tid + i * 256];
    __syncthreads();

    long long u = (long long)blockIdx.x * blockDim.x + threadIdx.x;
    if (u >= total_units) return;
    const int e = (int)(u >> 5);
    const int c = (int)(u & 31);
    const int s  = esrc[e];
    const int d  = edst[e];
    const float w = ew[e];

    const float4* xr = (const float4*)(x + (size_t)s * IN_F);
    float acc = 0.f;
    #pragma unroll
    for (int k4 = 0; k4 < IN_F / 4; ++k4) {
        const float4 xv = xr[k4];
        acc += xv.x * Wl[(k4 * 4 + 0) * OUT_F + c];
        acc += xv.y * Wl[(k4 * 4 + 1) * OUT_F + c];
        acc += xv.z * Wl[(k4 * 4 + 2) * OUT_F + c];
        acc += xv.w * Wl[(k4 * 4 + 3) * OUT_F + c];
    }
    atomicAdd(out + (size_t)d * OUT_F + c, w * acc);
}

static inline size_t align_up(size_t v, size_t a) { return (v + a - 1) & ~(a - 1); }

extern "C" void kernel_launch(void* const* d_in, const int* in_sizes, int n_in,
                              void* d_out, int out_size, void* d_ws, size_t ws_size,
                              hipStream_t stream)
{
    const float* x  = (const float*)d_in[0];
    const float* W  = (const float*)d_in[1];
    const int* esrc = (const int*)d_in[2];
    const int* edst = (const int*)d_in[3];
    const float* ew = (const float*)d_in[4];
    float* out = (float*)d_out;

    const int n_nodes = in_sizes[0] / IN_F;
    const int n_edges = in_sizes[2];

    const int nb       = (n_nodes + NPB - 1) >> BSHIFT;    // 1563
    const int n_chunks = (n_edges + CHUNK - 1) / CHUNK;    // 391

    const size_t h_bytes    = align_up((size_t)n_nodes * OUT_F * sizeof(unsigned short), 256);
    const size_t cnt_bytes  = align_up((size_t)nb * n_chunks * sizeof(int), 256);
    const size_t off_bytes  = align_up((size_t)nb * n_chunks * sizeof(int), 256);
    const size_t tot_bytes  = align_up((size_t)nb * sizeof(int), 256);
    const size_t col_bytes  = align_up(((size_t)nb + 1) * sizeof(int), 256);
    const size_t recs_bytes = align_up(((size_t)n_edges + 32 * (size_t)nb) * sizeof(int2), 256);
    const size_t need = h_bytes + cnt_bytes + off_bytes + tot_bytes + col_bytes + recs_bytes;

    if (ws_size >= need && nb <= MAXB && n_chunks <= 512) {
        char* p = (char*)d_ws;
        unsigned short* h = (unsigned short*)p;  p += h_bytes;
        int* cntT     = (int*)p;                 p += cnt_bytes;
        int* offT     = (int*)p;                 p += off_bytes;
        int* totals   = (int*)p;                 p += tot_bytes;
        int* colStart = (int*)p;                 p += col_bytes;
        int2* recs    = (int2*)p;

        // pad slots must be zero-records each call
        hipMemsetAsync(recs, 0, recs_bytes, stream);

        const int gemm_blocks = (n_nodes + 31) / 32;
        gcn_gemm_h<<<gemm_blocks, 256, 0, stream>>>(x, W, h, n_nodes);

        gcn_count<<<n_chunks, BIN_THREADS, 0, stream>>>(edst, cntT, n_edges, nb, n_chunks);
        gcn_scan_bucket<<<nb, 512, 0, stream>>>(cntT, offT, totals, n_chunks, nb);
        gcn_scan_total<<<1, 1024, 0, stream>>>(totals, colStart, nb);
        gcn_bin<<<n_chunks, BIN_THREADS, 0, stream>>>(esrc, edst, ew, colStart, offT,
                                                      recs, n_edges, nb, n_chunks);
        gcn_aggregate<<<nb, AGG_THREADS, 0, stream>>>(h, recs, colStart, out, n_nodes);
    } else {
        hipMemsetAsync(d_out, 0, (size_t)out_size * sizeof(float), stream);
        const long long total_units = (long long)n_edges * 32;
        const int fblocks = (int)((total_units + 255) / 256);
        gcn_fused_fallback<<<fblocks, 256, 0, stream>>>(x, W, esrc, edst, ew, out, total_units);
    }
}

// Round 6
// 682.782 us; speedup vs baseline: 1.0929x; 1.0127x over previous
//
#include <hip/hip_runtime.h>
#include <hip/hip_bf16.h>

#define IN_F 128
#define OUT_F 32
#define BSHIFT 6
#define NPB 64             // nodes per bucket (dst >> 6)
#define CHUNK 8192         // edges per chunk
#define BIN_THREADS 512
#define AGG_THREADS 256
#define ACC_STRIDE 33      // bank = (dL + c) & 31 -> conflict-free per edge
#define MAXB 2048
#define DEPTH 8            // explicit MLP depth in aggregate

static __device__ inline unsigned short f2bf_rne(float f) {
    unsigned u = __float_as_uint(f);
    unsigned r = u + 0x7FFF + ((u >> 16) & 1);   // round-to-nearest-even
    return (unsigned short)(r >> 16);
}

// ---------------- K1: h = x @ W, output bf16 (W staged in LDS) ----------------
__global__ void gcn_gemm_h(const float* __restrict__ x, const float* __restrict__ W,
                           unsigned short* __restrict__ h, int n_rows)
{
    __shared__ float Wl[IN_F * OUT_F];           // 16 KB
    const int tid = threadIdx.x;
    const float4* W4 = (const float4*)W;
    float4* Wl4 = (float4*)Wl;
    #pragma unroll
    for (int i = 0; i < 4; ++i)
        Wl4[tid + i * 256] = W4[tid + i * 256];
    __syncthreads();

    const int c4   = tid & 7;
    const int rloc = tid >> 3;
    const int row  = blockIdx.x * 32 + rloc;
    if (row >= n_rows) return;

    const float4* xr = (const float4*)(x + (size_t)row * IN_F);
    float4 acc = {0.f, 0.f, 0.f, 0.f};
    #pragma unroll
    for (int k4 = 0; k4 < IN_F / 4; ++k4) {
        const float4 xv = xr[k4];
        #pragma unroll
        for (int j = 0; j < 4; ++j) {
            const int k = k4 * 4 + j;
            const float4 wv = *(const float4*)(&Wl[k * OUT_F + c4 * 4]);
            const float xs = (&xv.x)[j];
            acc.x += xs * wv.x;
            acc.y += xs * wv.y;
            acc.z += xs * wv.z;
            acc.w += xs * wv.w;
        }
    }
    ushort4 o = { f2bf_rne(acc.x), f2bf_rne(acc.y), f2bf_rne(acc.z), f2bf_rne(acc.w) };
    *(ushort4*)(&h[(size_t)row * OUT_F + c4 * 4]) = o;
}

// ---------------- K2a: per-chunk histogram over buckets ----------------
__global__ __launch_bounds__(BIN_THREADS)
void gcn_count(const int* __restrict__ edst, int* __restrict__ cntT,
               int n_edges, int nb, int n_chunks)
{
    __shared__ int hist[MAXB];
    const int tid = threadIdx.x;
    const int k   = blockIdx.x;
    const int base  = k * CHUNK;
    const int count = min(CHUNK, n_edges - base);
    for (int i = tid; i < nb; i += BIN_THREADS) hist[i] = 0;
    __syncthreads();
    for (int i = tid; i < count; i += BIN_THREADS)
        atomicAdd(&hist[edst[base + i] >> BSHIFT], 1);
    __syncthreads();
    for (int i = tid; i < nb; i += BIN_THREADS)
        cntT[(size_t)i * n_chunks + k] = hist[i];      // [bucket][chunk]
}

// ---------------- K2b: per-bucket exclusive scan over chunks ----------------
__global__ __launch_bounds__(512)
void gcn_scan_bucket(const int* __restrict__ cntT, int* __restrict__ offT,
                     int* __restrict__ totals, int n_chunks, int nb)
{
    __shared__ int sh[512];
    const int b = blockIdx.x, tid = threadIdx.x;
    const int v = (tid < n_chunks) ? cntT[(size_t)b * n_chunks + tid] : 0;
    sh[tid] = v;
    __syncthreads();
    for (int off = 1; off < 512; off <<= 1) {
        int t = (tid >= off) ? sh[tid - off] : 0;
        __syncthreads();
        sh[tid] += t;
        __syncthreads();
    }
    if (tid < n_chunks) offT[(size_t)tid * nb + b] = sh[tid] - v;   // [chunk][bucket]
    if (tid == 511) totals[b] = sh[511];
}

// ---------------- K2c: exclusive scan of ROUNDED bucket totals ----------------
__global__ __launch_bounds__(1024)
void gcn_scan_total(const int* __restrict__ totals, int* __restrict__ colStart, int nb)
{
    __shared__ int sh[1024];
    __shared__ int carry_s;
    const int tid = threadIdx.x;
    if (tid == 0) carry_s = 0;
    __syncthreads();
    for (int base = 0; base < nb; base += 1024) {
        const int idx = base + tid;
        const int v = (idx < nb) ? ((totals[idx] + 31) & ~31) : 0;
        sh[tid] = v;
        __syncthreads();
        for (int off = 1; off < 1024; off <<= 1) {
            int t = (tid >= off) ? sh[tid - off] : 0;
            __syncthreads();
            sh[tid] += t;
            __syncthreads();
        }
        const int carry = carry_s;
        if (idx < nb) colStart[idx] = carry + sh[tid] - v;
        __syncthreads();
        if (tid == 1023) carry_s = carry + sh[1023];
        __syncthreads();
    }
    if (tid == 0) colStart[nb] = carry_s;
}

// ---------------- K2c2: zero only the pad slots ----------------
__global__ __launch_bounds__(64)
void gcn_padzero(const int* __restrict__ colStart, const int* __restrict__ totals,
                 int2* __restrict__ recs)
{
    const int b = blockIdx.x;
    const int start = colStart[b] + totals[b];
    const int end   = colStart[b + 1];
    const int t = threadIdx.x;
    if (start + t < end) recs[start + t] = make_int2(0, 0);
}

// ---------------- K2d: write records to final bucket-major slots ----------------
// Record: {src | (dstLocal<<17), w_bits}  (src < 2^17, dstLocal < 2^6)
__global__ __launch_bounds__(BIN_THREADS)
void gcn_bin(const int* __restrict__ esrc, const int* __restrict__ edst,
             const float* __restrict__ ew,
             const int* __restrict__ colStart, const int* __restrict__ offT,
             int2* __restrict__ recs, int n_edges, int nb, int n_chunks)
{
    __shared__ int cursor[MAXB];
    const int tid = threadIdx.x;
    const int k   = blockIdx.x;
    const int* offRow = offT + (size_t)k * nb;
    for (int i = tid; i < nb; i += BIN_THREADS)
        cursor[i] = colStart[i] + offRow[i];
    __syncthreads();

    const int base  = k * CHUNK;
    const int count = min(CHUNK, n_edges - base);
    for (int i = tid; i < count; i += BIN_THREADS) {
        const int e = base + i;
        const int d = edst[e];
        const int pos = atomicAdd(&cursor[d >> BSHIFT], 1);
        recs[pos] = make_int2(esrc[e] | ((d & (NPB - 1)) << 17), __float_as_int(ew[e]));
    }
}

// ---------------- K3: one block per bucket; half-wave owns one edge ----------------
// Explicit 8-deep software pipeline: 8 rec loads -> 8 h loads -> 8 ds_add.
__global__ __launch_bounds__(AGG_THREADS, 4)
void gcn_aggregate(const unsigned short* __restrict__ h,
                   const int2* __restrict__ recs,
                   const int* __restrict__ colStart,
                   float* __restrict__ out, int n_nodes)
{
    __shared__ float acc[NPB * ACC_STRIDE];      // 8.4 KB
    const int b   = blockIdx.x;
    const int tid = threadIdx.x;

    for (int i = tid; i < NPB * ACC_STRIDE; i += AGG_THREADS) acc[i] = 0.f;
    __syncthreads();

    const int s = colStart[b];
    const int nGroups = (colStart[b + 1] - s) >> 5;   // padded to multiple of 32
    const int hw = tid >> 5;                          // 8 half-waves per block
    const int c  = tid & 31;                          // channel

    for (int g = hw; g < nGroups; g += AGG_THREADS / 32) {
        const int2* rp = recs + s + (g << 5);
        #pragma unroll
        for (int half = 0; half < 32 / DEPTH; ++half) {
            int2 r0 = rp[half * DEPTH + 0];
            int2 r1 = rp[half * DEPTH + 1];
            int2 r2 = rp[half * DEPTH + 2];
            int2 r3 = rp[half * DEPTH + 3];
            int2 r4 = rp[half * DEPTH + 4];
            int2 r5 = rp[half * DEPTH + 5];
            int2 r6 = rp[half * DEPTH + 6];
            int2 r7 = rp[half * DEPTH + 7];

            unsigned u0 = h[((size_t)(r0.x & 0x1FFFF) << 5) + c];
            unsigned u1 = h[((size_t)(r1.x & 0x1FFFF) << 5) + c];
            unsigned u2 = h[((size_t)(r2.x & 0x1FFFF) << 5) + c];
            unsigned u3 = h[((size_t)(r3.x & 0x1FFFF) << 5) + c];
            unsigned u4 = h[((size_t)(r4.x & 0x1FFFF) << 5) + c];
            unsigned u5 = h[((size_t)(r5.x & 0x1FFFF) << 5) + c];
            unsigned u6 = h[((size_t)(r6.x & 0x1FFFF) << 5) + c];
            unsigned u7 = h[((size_t)(r7.x & 0x1FFFF) << 5) + c];

            atomicAdd(&acc[((r0.x >> 17) & (NPB - 1)) * ACC_STRIDE + c],
                      __int_as_float(r0.y) * __uint_as_float(u0 << 16));
            atomicAdd(&acc[((r1.x >> 17) & (NPB - 1)) * ACC_STRIDE + c],
                      __int_as_float(r1.y) * __uint_as_float(u1 << 16));
            atomicAdd(&acc[((r2.x >> 17) & (NPB - 1)) * ACC_STRIDE + c],
                      __int_as_float(r2.y) * __uint_as_float(u2 << 16));
            atomicAdd(&acc[((r3.x >> 17) & (NPB - 1)) * ACC_STRIDE + c],
                      __int_as_float(r3.y) * __uint_as_float(u3 << 16));
            atomicAdd(&acc[((r4.x >> 17) & (NPB - 1)) * ACC_STRIDE + c],
                      __int_as_float(r4.y) * __uint_as_float(u4 << 16));
            atomicAdd(&acc[((r5.x >> 17) & (NPB - 1)) * ACC_STRIDE + c],
                      __int_as_float(r5.y) * __uint_as_float(u5 << 16));
            atomicAdd(&acc[((r6.x >> 17) & (NPB - 1)) * ACC_STRIDE + c],
                      __int_as_float(r6.y) * __uint_as_float(u6 << 16));
            atomicAdd(&acc[((r7.x >> 17) & (NPB - 1)) * ACC_STRIDE + c],
                      __int_as_float(r7.y) * __uint_as_float(u7 << 16));
        }
    }
    __syncthreads();

    const int nodeBase = b << BSHIFT;
    const int nvalid   = min(NPB, n_nodes - nodeBase);
    for (int i = tid; i < (nvalid * OUT_F) / 4; i += AGG_THREADS) {
        const int node = (i * 4) >> 5;
        const int cc   = (i * 4) & 31;
        const float* ap = acc + node * ACC_STRIDE + cc;
        float4 v = { ap[0], ap[1], ap[2], ap[3] };
        *(float4*)(out + ((size_t)(nodeBase + node) << 5) + cc) = v;
    }
}

// ---------------- Fallback (no/small ws): fused, atomics into out ----------------
__global__ void gcn_fused_fallback(const float* __restrict__ x, const float* __restrict__ W,
                                   const int* __restrict__ esrc,
                                   const int* __restrict__ edst,
                                   const float* __restrict__ ew,
                                   float* __restrict__ out,
                                   long long total_units)
{
    __shared__ float Wl[IN_F * OUT_F];
    const int tid = threadIdx.x;
    const float4* W4 = (const float4*)W;
    float4* Wl4 = (float4*)Wl;
    #pragma unroll
    for (int i = 0; i < 4; ++i)
        Wl4[tid + i * 256] = W4[tid + i * 256];
    __syncthreads();

    long long u = (long long)blockIdx.x * blockDim.x + threadIdx.x;
    if (u >= total_units) return;
    const int e = (int)(u >> 5);
    const int c = (int)(u & 31);
    const int s  = esrc[e];
    const int d  = edst[e];
    const float w = ew[e];

    const float4* xr = (const float4*)(x + (size_t)s * IN_F);
    float acc = 0.f;
    #pragma unroll
    for (int k4 = 0; k4 < IN_F / 4; ++k4) {
        const float4 xv = xr[k4];
        acc += xv.x * Wl[(k4 * 4 + 0) * OUT_F + c];
        acc += xv.y * Wl[(k4 * 4 + 1) * OUT_F + c];
        acc += xv.z * Wl[(k4 * 4 + 2) * OUT_F + c];
        acc += xv.w * Wl[(k4 * 4 + 3) * OUT_F + c];
    }
    atomicAdd(out + (size_t)d * OUT_F + c, w * acc);
}

static inline size_t align_up(size_t v, size_t a) { return (v + a - 1) & ~(a - 1); }

extern "C" void kernel_launch(void* const* d_in, const int* in_sizes, int n_in,
                              void* d_out, int out_size, void* d_ws, size_t ws_size,
                              hipStream_t stream)
{
    const float* x  = (const float*)d_in[0];
    const float* W  = (const float*)d_in[1];
    const int* esrc = (const int*)d_in[2];
    const int* edst = (const int*)d_in[3];
    const float* ew = (const float*)d_in[4];
    float* out = (float*)d_out;

    const int n_nodes = in_sizes[0] / IN_F;
    const int n_edges = in_sizes[2];

    const int nb       = (n_nodes + NPB - 1) >> BSHIFT;    // 1563
    const int n_chunks = (n_edges + CHUNK - 1) / CHUNK;    // 391

    const size_t h_bytes    = align_up((size_t)n_nodes * OUT_F * sizeof(unsigned short), 256);
    const size_t cnt_bytes  = align_up((size_t)nb * n_chunks * sizeof(int), 256);
    const size_t off_bytes  = align_up((size_t)nb * n_chunks * sizeof(int), 256);
    const size_t tot_bytes  = align_up((size_t)nb * sizeof(int), 256);
    const size_t col_bytes  = align_up(((size_t)nb + 1) * sizeof(int), 256);
    const size_t recs_bytes = align_up(((size_t)n_edges + 32 * (size_t)nb) * sizeof(int2), 256);
    const size_t need = h_bytes + cnt_bytes + off_bytes + tot_bytes + col_bytes + recs_bytes;

    if (ws_size >= need && nb <= MAXB && n_chunks <= 512) {
        char* p = (char*)d_ws;
        unsigned short* h = (unsigned short*)p;  p += h_bytes;
        int* cntT     = (int*)p;                 p += cnt_bytes;
        int* offT     = (int*)p;                 p += off_bytes;
        int* totals   = (int*)p;                 p += tot_bytes;
        int* colStart = (int*)p;                 p += col_bytes;
        int2* recs    = (int2*)p;

        const int gemm_blocks = (n_nodes + 31) / 32;
        gcn_gemm_h<<<gemm_blocks, 256, 0, stream>>>(x, W, h, n_nodes);

        gcn_count<<<n_chunks, BIN_THREADS, 0, stream>>>(edst, cntT, n_edges, nb, n_chunks);
        gcn_scan_bucket<<<nb, 512, 0, stream>>>(cntT, offT, totals, n_chunks, nb);
        gcn_scan_total<<<1, 1024, 0, stream>>>(totals, colStart, nb);
        gcn_padzero<<<nb, 64, 0, stream>>>(colStart, totals, recs);
        gcn_bin<<<n_chunks, BIN_THREADS, 0, stream>>>(esrc, edst, ew, colStart, offT,
                                                      recs, n_edges, nb, n_chunks);
        gcn_aggregate<<<nb, AGG_THREADS, 0, stream>>>(h, recs, colStart, out, n_nodes);
    } else {
        hipMemsetAsync(d_out, 0, (size_t)out_size * sizeof(float), stream);
        const long long total_units = (long long)n_edges * 32;
        const int fblocks = (int)((total_units + 255) / 256);
        gcn_fused_fallback<<<fblocks, 256, 0, stream>>>(x, W, esrc, edst, ew, out, total_units);
    }
}